// Round 1
// baseline (248.307 us; speedup 1.0000x reference)
//
#include <hip/hip_runtime.h>

namespace {

constexpr int NS = 256;      // samples
constexpr int MP = 128;      // patches
constexpr int TSTEPS = 200;  // timesteps
constexpr int BLK = 256;     // threads per block

__device__ __forceinline__ float4 ldg4(const float* p) {
  return *reinterpret_cast<const float4*>(p);
}

__global__ __launch_bounds__(BLK, 1)
void sir_meta_kernel(const float* __restrict__ Rg,
                     const float* __restrict__ Tg,
                     const float* __restrict__ rho0g,
                     const float* __restrict__ betag,
                     float* __restrict__ outg)
{
  __shared__ __align__(16) float rs[MP];     // 1/rowsum
  __shared__ __align__(16) float binv[MP];   // beta/neff
  __shared__ __align__(16) float scr[BLK];
  __shared__ __align__(16) float x0[MP];     // rho[:,0] double buffer
  __shared__ __align__(16) float x1[MP];
  __shared__ float4 outbuf[16][MP];          // 16-step output ring (32 KB)

  const int tid = threadIdx.x;
  const int n = blockIdx.x;
  const float* __restrict__ Rn = Rg + (size_t)n * MP * MP;
  const float beta = betag[n];

  // ---- S1: row sums (coalesced, shfl-reduced) -> rs = 1/rowsum ----
  {
    const int wave = tid >> 6;
    const int lane = tid & 63;
    const int half = lane >> 5;   // lanes 0-31: even row of pair, 32-63: odd
    const int l32 = lane & 31;
    for (int it = 0; it < 16; ++it) {
      const int row = wave * 32 + it * 2 + half;
      float4 v = ldg4(Rn + row * MP + l32 * 4);
      float s = (v.x + v.y) + (v.z + v.w);
      s += __shfl_xor(s, 1);
      s += __shfl_xor(s, 2);
      s += __shfl_xor(s, 4);
      s += __shfl_xor(s, 8);
      s += __shfl_xor(s, 16);
      if (l32 == 0) rs[row] = 1.0f / s;
    }
  }
  __syncthreads();

  // ---- S2: neff[k] = sum_i Rraw[i][k]*rs[i] (coalesced) -> binv = beta/neff
  {
    const int k = tid & 127;
    const int h = tid >> 7;
    float acc = 0.0f;
    #pragma unroll 8
    for (int i = 0; i < 64; ++i) {
      const int ig = h * 64 + i;
      acc = fmaf(Rn[ig * MP + k], rs[ig], acc);
    }
    scr[tid] = acc;
  }
  __syncthreads();
  if (tid < 128) binv[tid] = beta / (scr[tid] + scr[tid + 128]);
  __syncthreads();

  // ---- S3: build G row-half in registers:
  // w[i] = rs[j]*rs[ihb+i] * sum_k Rraw[j][k]*binv[k]*Rraw[ihb+i][k]
  const int j = tid >> 1;          // owned row
  const int ihb = (tid & 1) * 64;  // column half of G
  float w[64];
  #pragma unroll
  for (int q = 0; q < 64; ++q) w[q] = 0.0f;

  for (int kc = 0; kc < 4; ++kc) {
    float4 a[8];
    #pragma unroll
    for (int q = 0; q < 8; ++q) {
      float4 rv = ldg4(Rn + j * MP + kc * 32 + q * 4);
      float4 bv = *reinterpret_cast<const float4*>(&binv[kc * 32 + q * 4]);
      a[q].x = rv.x * bv.x; a[q].y = rv.y * bv.y;
      a[q].z = rv.z * bv.z; a[q].w = rv.w * bv.w;
    }
    #pragma unroll
    for (int i = 0; i < 64; ++i) {
      const float* src = Rn + (ihb + i) * MP + kc * 32;
      float acc = 0.0f;
      #pragma unroll
      for (int q = 0; q < 8; ++q) {
        float4 b = ldg4(src + q * 4);
        acc = fmaf(a[q].x, b.x, acc);
        acc = fmaf(a[q].y, b.y, acc);
        acc = fmaf(a[q].z, b.z, acc);
        acc = fmaf(a[q].w, b.w, acc);
      }
      w[i] += acc;
    }
  }
  {
    const float rj = rs[j];
    #pragma unroll
    for (int i = 0; i < 64; ++i) w[i] *= rj * rs[ihb + i];
  }

  // ---- S4: init state (both lanes of a pair hold row j's rho) ----
  float r0 = rho0g[((size_t)n * MP + j) * 3 + 0];
  float r1 = rho0g[((size_t)n * MP + j) * 3 + 1];
  float r2 = rho0g[((size_t)n * MP + j) * 3 + 2];
  const float T00 = Tg[n*9+0], T01 = Tg[n*9+1], T02 = Tg[n*9+2];
  const float T10 = Tg[n*9+3], T11 = Tg[n*9+4], T12 = Tg[n*9+5];
  const float T20 = Tg[n*9+6], T21 = Tg[n*9+7], T22 = Tg[n*9+8];
  if ((tid & 1) == 0) x0[j] = r0;
  __syncthreads();

  float4* __restrict__ outg4 = reinterpret_cast<float4*>(outg);
  const size_t outbase = (size_t)n * TSTEPS * MP;

  int slot = 0;
  for (int s = 0; s < TSTEPS; ++s) {
    const float* xc = (s & 1) ? x1 : x0;
    float* xn = (s & 1) ? x0 : x1;

    // E: half-row matvec from registers, broadcast x from LDS
    float a0 = 0.0f, a1 = 0.0f, a2 = 0.0f, a3 = 0.0f;
    const float4* xv = reinterpret_cast<const float4*>(xc + ihb);
    #pragma unroll
    for (int q = 0; q < 16; ++q) {
      float4 x = xv[q];
      a0 = fmaf(w[4*q+0], x.x, a0);
      a1 = fmaf(w[4*q+1], x.y, a1);
      a2 = fmaf(w[4*q+2], x.z, a2);
      a3 = fmaf(w[4*q+3], x.w, a3);
    }
    float acc = (a0 + a1) + (a2 + a3);
    float rp = acc + __shfl_xor(acc, 1);  // combine the two column halves

    // F: output (pre-update state) + state update; both lanes redundant
    const float S = 1.0f - ((r0 + r1) + r2);
    if (tid & 1) {
      float4 o; o.x = S; o.y = r0; o.z = r1; o.w = r2;
      outbuf[slot][j] = o;
    }
    const float ni = S * rp;
    float n0 = fmaf(r0, T00, fmaf(r1, T10, fmaf(r2, T20, ni)));
    float n1 = fmaf(r0, T01, fmaf(r1, T11, r2 * T21));
    float n2 = fmaf(r0, T02, fmaf(r1, T12, r2 * T22));
    n0 = fminf(fmaxf(n0, 0.0f), 1.0f);
    n1 = fminf(fmaxf(n1, 0.0f), 1.0f);
    n2 = fminf(fmaxf(n2, 0.0f), 1.0f);
    r0 = n0; r1 = n1; r2 = n2;
    if ((tid & 1) == 0) xn[j] = n0;

    if (slot == 15 || s == TSTEPS - 1) {
      __syncthreads();  // make this step's outbuf writes visible
      const int cnt = (slot + 1) * MP;  // float4 count to flush
      const int sbase = s - slot;
      for (int e = tid; e < cnt; e += BLK) {
        outg4[outbase + (size_t)sbase * MP + e] = outbuf[e >> 7][e & 127];
      }
      slot = 0;
      __syncthreads();  // flush reads done before ring reuse; xn visible
    } else {
      ++slot;
      __syncthreads();  // xn visible for next step's E
    }
  }
}

} // namespace

extern "C" void kernel_launch(void* const* d_in, const int* in_sizes, int n_in,
                              void* d_out, int out_size, void* d_ws, size_t ws_size,
                              hipStream_t stream)
{
  const float* Rg    = (const float*)d_in[0];
  const float* Tg    = (const float*)d_in[1];
  const float* rho0g = (const float*)d_in[2];
  const float* betag = (const float*)d_in[3];
  float* outg = (float*)d_out;
  sir_meta_kernel<<<NS, BLK, 0, stream>>>(Rg, Tg, rho0g, betag, outg);
}